// Round 1
// baseline (324.523 us; speedup 1.0000x reference)
//
#include <hip/hip_runtime.h>

// Problem constants (fixed by reference setup_inputs)
#define B_  8
#define T_  1000
#define F_  257
#define TP  (T_ + 2)   // 1002 (causal pad: 2 at top of time)
#define FP  (F_ + 2)   // 259  (freq pad: 1 each side)
#define SQ3_2 0.8660254037844386f

// ---------------------------------------------------------------------------
// Pass 1: x (B, F, T, 2) fp32  ->  padded XP (B, TP, FP) float2
//   XP[b][tp][fp] = xc[b][tp-2][fp-1]  (zero outside)
// LDS-tiled transpose: reads coalesced along t, writes coalesced along f.
// ---------------------------------------------------------------------------
__global__ __launch_bounds__(256)
void transpose_pad(const float2* __restrict__ x, float2* __restrict__ xp) {
    __shared__ float2 tile[32][33];   // +1 pad breaks bank-conflict stride
    const int b   = blockIdx.z;
    const int tp0 = blockIdx.x * 32;  // padded-time tile origin
    const int fp0 = blockIdx.y * 32;  // padded-freq tile origin
    const int tx  = threadIdx.x;      // 0..31
    const int ty  = threadIdx.y;      // 0..7

    // Read phase: lanes along t (x is contiguous in t for fixed f)
    #pragma unroll
    for (int k = 0; k < 4; ++k) {
        const int fl = ty + k * 8;        // local f  (0..31)
        const int t  = tp0 + tx - 2;      // unpadded time
        const int f  = fp0 + fl - 1;      // unpadded freq
        float2 v = make_float2(0.f, 0.f);
        if (t >= 0 && t < T_ && f >= 0 && f < F_)
            v = x[(size_t)(b * F_ + f) * T_ + t];
        tile[fl][tx] = v;
    }
    __syncthreads();

    // Write phase: lanes along fp (XP contiguous in fp); pad written as zeros
    #pragma unroll
    for (int k = 0; k < 4; ++k) {
        const int tp = tp0 + ty + k * 8;
        const int fp = fp0 + tx;
        if (tp < TP && fp < FP)
            xp[((size_t)b * TP + tp) * FP + fp] = tile[tx][ty + k * 8];
    }
}

// ---------------------------------------------------------------------------
// Pass 2: main fused mask+stencil.
// Block = 64 f-lanes x 8 t-rows (512 threads).
//   - 27 m loads per thread, coalesced along f (dominant 222 MB stream)
//   - 9 float2 taps from padded XP, coalesced along f
//   - output staged through LDS so global writes coalesce along t
// ---------------------------------------------------------------------------
__global__ __launch_bounds__(512)
void ccm_main(const float* __restrict__ m, const float2* __restrict__ xp,
              float2* __restrict__ out) {
    __shared__ float2 stage[8][66];   // stride 66 -> conflict-light reads

    const int b   = blockIdx.z;
    const int f0  = blockIdx.x * 64;
    const int t0  = blockIdx.y * 8;
    const int tid = threadIdx.x;
    const int lf  = tid & 63;         // lane's f within tile
    const int lt  = tid >> 6;         // lane's t within tile
    const int f   = f0 + lf;
    const int t   = t0 + lt;

    float accr = 0.f, acci = 0.f;

    if (f < F_) {
        // 9 stencil taps (padded coords: tap(mm,nn) at (t+mm, f+nn))
        const float2* xpb = xp + (size_t)b * TP * FP;
        float2 tap[3][3];
        #pragma unroll
        for (int mm = 0; mm < 3; ++mm)
            #pragma unroll
            for (int nn = 0; nn < 3; ++nn)
                tap[mm][nn] = xpb[(size_t)(t + mm) * FP + (f + nn)];

        // 27 mask-plane loads; H[c] = m0 - 0.5(m1+m2) + i*(sqrt3/2)(m1-m2)
        const float* mb = m + ((size_t)b * 27 * T_ + t) * F_ + f;
        #pragma unroll
        for (int c = 0; c < 9; ++c) {
            const float m0 = mb[(size_t)(c)      * (T_ * F_)];
            const float m1 = mb[(size_t)(c + 9)  * (T_ * F_)];
            const float m2 = mb[(size_t)(c + 18) * (T_ * F_)];
            const float hr = m0 - 0.5f * (m1 + m2);
            const float hi = SQ3_2 * (m1 - m2);
            const float2 xv = tap[c / 3][c % 3];
            accr = fmaf(hr, xv.x, accr);
            accr = fmaf(-hi, xv.y, accr);
            acci = fmaf(hr, xv.y, acci);
            acci = fmaf(hi, xv.x, acci);
        }
    }

    // Stage in LDS, then write out (B,F,T,2) with lanes along t:
    // 8 consecutive t (x float2) = 64 B contiguous per f.
    stage[lt][lf] = make_float2(accr, acci);
    __syncthreads();

    const int wf = tid >> 3;          // 0..63
    const int wt = tid & 7;           // 0..7
    if (f0 + wf < F_)
        out[(size_t)(b * F_ + f0 + wf) * T_ + (t0 + wt)] = stage[wt][wf];
}

extern "C" void kernel_launch(void* const* d_in, const int* in_sizes, int n_in,
                              void* d_out, int out_size, void* d_ws, size_t ws_size,
                              hipStream_t stream) {
    const float*  m = (const float*)d_in[0];   // (B, 27, T, F) fp32
    const float2* x = (const float2*)d_in[1];  // (B, F, T, 2) fp32 -> float2
    float2* out = (float2*)d_out;              // (B, F, T, 2) fp32 -> float2
    float2* xp  = (float2*)d_ws;               // (B, TP, FP) float2, 16.6 MB

    dim3 tb(32, 8);
    dim3 tg((TP + 31) / 32, (FP + 31) / 32, B_);   // 32 x 9 x 8
    transpose_pad<<<tg, tb, 0, stream>>>(x, xp);

    dim3 mb(512);
    dim3 mg((F_ + 63) / 64, T_ / 8, B_);           // 5 x 125 x 8
    ccm_main<<<mg, mb, 0, stream>>>(m, xp, out);
}

// Round 2
// 321.330 us; speedup vs baseline: 1.0099x; 1.0099x over previous
//
#include <hip/hip_runtime.h>

// Problem constants (fixed by reference setup_inputs)
#define B_  8
#define T_  1000
#define F_  257
#define SQ3_2 0.8660254037844386f

// ---------------------------------------------------------------------------
// Fully fused: pad + transpose (via LDS halo staging) + 3x3 complex mask MAC
// + output transpose (via LDS staging).
//
// Block = 64 f-lanes x 8 t-rows (512 threads). Grid (5, 125, 8).
//   - x halo (10 t x 66 f float2) staged into LDS; x reads coalesced along t
//     (its contiguous axis), 80 B contiguous per f-row.
//   - 27 m loads per thread, coalesced along f (m's contiguous axis; this is
//     the dominant 222 MB stream).
//   - out staged through LDS so global writes coalesce along t (64 B chunks).
// ---------------------------------------------------------------------------
__global__ __launch_bounds__(512)
void ccm_fused(const float* __restrict__ m, const float2* __restrict__ x,
               float2* __restrict__ out) {
    __shared__ float2 xls[10 * 66];   // [r][j]: r = t0+r-2, j = f0+j-1
    __shared__ float2 stage[8][66];   // output transpose staging

    const int b   = blockIdx.z;
    const int f0  = blockIdx.x * 64;
    const int t0  = blockIdx.y * 8;
    const int tid = threadIdx.x;
    const int lf  = tid & 63;         // lane's f within tile
    const int lt  = tid >> 6;         // lane's t within tile
    const int f   = f0 + lf;
    const int t   = t0 + lt;

    // ---- Stage x halo into LDS ----
    // idx = j*10 + r: r fast => consecutive lanes hit consecutive t
    // (x is contiguous in t), 10 float2 = 80 B per f-row.
    const float2* xb = x + (size_t)b * F_ * T_;
    #pragma unroll
    for (int pass = 0; pass < 2; ++pass) {
        const int idx = tid + pass * 512;
        if (idx < 660) {
            const int j = idx / 10;
            const int r = idx - j * 10;
            const int tt = t0 + r - 2;
            const int ff = f0 + j - 1;
            float2 v = make_float2(0.f, 0.f);
            if (tt >= 0 && tt < T_ && ff >= 0 && ff < F_)
                v = xb[(size_t)ff * T_ + tt];
            xls[r * 66 + j] = v;      // row-major, j fast: tap reads conflict-free
        }
    }
    __syncthreads();

    float accr = 0.f, acci = 0.f;

    if (f < F_) {
        // 27 mask-plane loads; H[c] = m0 - 0.5(m1+m2) + i*(sqrt3/2)(m1-m2)
        // tap(c) = xls[lt + c/3][lf + c%3]
        const float* mb = m + ((size_t)b * 27 * T_ + t) * F_ + f;
        #pragma unroll
        for (int c = 0; c < 9; ++c) {
            const float m0 = mb[(size_t)(c)      * (T_ * F_)];
            const float m1 = mb[(size_t)(c + 9)  * (T_ * F_)];
            const float m2 = mb[(size_t)(c + 18) * (T_ * F_)];
            const float hr = m0 - 0.5f * (m1 + m2);
            const float hi = SQ3_2 * (m1 - m2);
            const float2 xv = xls[(lt + c / 3) * 66 + (lf + c % 3)];
            accr = fmaf(hr, xv.x, accr);
            accr = fmaf(-hi, xv.y, accr);
            acci = fmaf(hr, xv.y, acci);
            acci = fmaf(hi, xv.x, acci);
        }
    }

    // ---- Stage output in LDS, write coalesced along t ----
    stage[lt][lf] = make_float2(accr, acci);
    __syncthreads();

    const int wf = tid >> 3;          // 0..63
    const int wt = tid & 7;           // 0..7
    if (f0 + wf < F_)
        out[(size_t)(b * F_ + f0 + wf) * T_ + (t0 + wt)] = stage[wt][wf];
}

extern "C" void kernel_launch(void* const* d_in, const int* in_sizes, int n_in,
                              void* d_out, int out_size, void* d_ws, size_t ws_size,
                              hipStream_t stream) {
    const float*  m = (const float*)d_in[0];   // (B, 27, T, F) fp32
    const float2* x = (const float2*)d_in[1];  // (B, F, T, 2) fp32 -> float2
    float2* out = (float2*)d_out;              // (B, F, T, 2) fp32 -> float2

    dim3 mb(512);
    dim3 mg((F_ + 63) / 64, T_ / 8, B_);       // 5 x 125 x 8
    ccm_fused<<<mg, mb, 0, stream>>>(m, x, out);
}